// Round 1
// baseline (1606.281 us; speedup 1.0000x reference)
//
#include <hip/hip_runtime.h>
#include <hip/hip_bf16.h>

#define TTOK 8192
#define HDIM 1024
#define ENUM 8
#define CAP  1280
#define IRD  4096
#define ISH  8192

typedef __hip_bfloat16 bf16;
typedef __bf16 bf16x8 __attribute__((ext_vector_type(8)));
typedef float f32x4 __attribute__((ext_vector_type(4)));

#define AS1(p) ((const __attribute__((address_space(1))) void*)(p))
#define AS3(p) ((__attribute__((address_space(3))) void*)(p))

// ---------------- router: RMSNorm (f32) + logits (f32) + top-2 ----------------
// Also emits x as bf16 for the expert GEMMs (experts consume UN-normalized x).
__global__ __launch_bounds__(256) void router_kernel(
    const float* __restrict__ x, const float* __restrict__ rtw,
    bf16* __restrict__ xb,
    int* __restrict__ e0a, int* __restrict__ e1a,
    float* __restrict__ w0a, float* __restrict__ w1a,
    int* __restrict__ s0a, int* __restrict__ s1a)
{
    __shared__ float row[HDIM];
    __shared__ float ssred[4];
    __shared__ float lgl[ENUM];
    const int t = blockIdx.x;
    const int tid = threadIdx.x;
    const int lane = tid & 63, wv = tid >> 6;
    const float* xr = x + (size_t)t * HDIM;
    bf16* xbr = xb + (size_t)t * HDIM;
    float ss = 0.f;
    for (int i = tid; i < HDIM; i += 256) {
        float v = xr[i];
        row[i] = v;
        ss += v * v;
        xbr[i] = __float2bfloat16(v);
    }
    #pragma unroll
    for (int o = 32; o > 0; o >>= 1) ss += __shfl_down(ss, o, 64);
    if (lane == 0) ssred[wv] = ss;
    __syncthreads();
    // wave wv handles experts 2*wv and 2*wv+1 (E=8, 4 waves)
    for (int ee = 0; ee < 2; ++ee) {
        const int e = wv * 2 + ee;
        const float* we = rtw + e * HDIM;
        float p = 0.f;
        for (int i = lane; i < HDIM; i += 64) p += row[i] * we[i];
        #pragma unroll
        for (int o = 32; o > 0; o >>= 1) p += __shfl_down(p, o, 64);
        if (lane == 0) lgl[e] = p;
    }
    __syncthreads();
    if (tid == 0) {
        float tot = ssred[0] + ssred[1] + ssred[2] + ssred[3];
        float rstd = rsqrtf(tot / (float)HDIM + 1.1920929e-07f);
        float l[ENUM];
        #pragma unroll
        for (int e = 0; e < ENUM; ++e) l[e] = lgl[e] * rstd;
        int b0 = 0;
        #pragma unroll
        for (int e = 1; e < ENUM; ++e) if (l[e] > l[b0]) b0 = e;  // strict > = lowest idx on tie
        int b1 = (b0 == 0) ? 1 : 0;
        #pragma unroll
        for (int e = 0; e < ENUM; ++e) if (e != b0 && l[e] > l[b1]) b1 = e;
        // top-2 renormalized softmax == 2-way softmax over the top-2 logits
        float w0 = 1.f / (1.f + expf(l[b1] - l[b0]));
        e0a[t] = b0; e1a[t] = b1;
        w0a[t] = w0; w1a[t] = 1.f - w0;
        s0a[t] = -1; s1a[t] = -1;
    }
}

// ------------- dispatch: stable (token-order) compaction per expert -----------
__global__ __launch_bounds__(256) void dispatch_kernel(
    const int* __restrict__ e0a, const int* __restrict__ e1a,
    int* __restrict__ disp, int* __restrict__ s0a, int* __restrict__ s1a)
{
    const int e = blockIdx.x;
    const int tid = threadIdx.x;
    const int lane = tid & 63, wv = tid >> 6;
    __shared__ int wcnt[4];
    for (int i = tid; i < CAP; i += 256) disp[e * CAP + i] = 0;  // safe filler token
    __syncthreads();
    int run = 0;
    for (int base = 0; base < TTOK; base += 256) {
        const int t = base + tid;
        const bool f0 = (e0a[t] == e);
        const bool f1 = (e1a[t] == e);
        const bool f = f0 || f1;
        unsigned long long m = __ballot(f);
        int posw = __popcll(m & ((1ULL << lane) - 1ULL));
        if (lane == 0) wcnt[wv] = __popcll(m);
        __syncthreads();
        int off = 0;
        #pragma unroll
        for (int w = 0; w < 4; ++w) if (w < wv) off += wcnt[w];
        const int tot = wcnt[0] + wcnt[1] + wcnt[2] + wcnt[3];
        if (f) {
            const int pos = run + off + posw;
            if (pos < CAP) {          // tokens beyond capacity are dropped
                disp[e * CAP + pos] = t;
                if (f0) s0a[t] = pos; else s1a[t] = pos;
            }
        }
        run += tot;
        __syncthreads();
    }
}

// ----------------------------- gather x rows ---------------------------------
__global__ __launch_bounds__(256) void gather_kernel(
    const int* __restrict__ disp, const bf16* __restrict__ xb, bf16* __restrict__ xg)
{
    const int r = blockIdx.x;             // 0 .. E*CAP-1
    const int t = disp[r];
    const uint2* s = (const uint2*)(xb + (size_t)t * HDIM);
    uint2* d = (uint2*)(xg + (size_t)r * HDIM);
    d[threadIdx.x] = s[threadIdx.x];      // 256 * 8B = 2 KB row
}

// --------------- f32 -> bf16 transpose-convert (weights to [N][K]) -----------
__global__ __launch_bounds__(256) void tcvt_kernel(
    const float* __restrict__ in, bf16* __restrict__ out, int R, int C)
{
    __shared__ float tile[32][33];
    const size_t boff = (size_t)blockIdx.z * R * C;
    const int c0 = blockIdx.x * 32, r0 = blockIdx.y * 32;
    const int tx = threadIdx.x & 31, ty = threadIdx.x >> 5;
    #pragma unroll
    for (int i = 0; i < 4; ++i)
        tile[ty + i * 8][tx] = in[boff + (size_t)(r0 + ty + i * 8) * C + c0 + tx];
    __syncthreads();
    #pragma unroll
    for (int i = 0; i < 4; ++i)
        out[boff + (size_t)(c0 + ty + i * 8) * R + r0 + tx] =
            __float2bfloat16(tile[tx][ty + i * 8]);
}

// -------- bf16 MFMA GEMM: C[M,N] = A[M,K] @ B^T, B given as [N][K] -----------
// 128x128 tile, BK=32, 4 waves each computing a 64x64 quadrant (4x4 of 16x16).
// Kept for the N=1024 "down" GEMMs where 256^2 tiles would under-fill the grid.
// EPI: 0 = store bf16; 1 = h = silu(Gaux)*acc, store bf16; 2 = store f32.
template <int EPI>
__global__ __launch_bounds__(256) void gemm_bt(
    const bf16* __restrict__ A, const bf16* __restrict__ B,
    void* __restrict__ Cv, const bf16* __restrict__ Gaux,
    int M, int N, int K, long long sA, long long sB, long long sC)
{
    __shared__ bf16 ldsA[128 * 32];
    __shared__ bf16 ldsB[128 * 32];
    const int z = blockIdx.z;
    const bf16* Ab = A + (long long)z * sA;
    const bf16* Bb = B + (long long)z * sB;
    const int tid = threadIdx.x;
    const int lane = tid & 63, wv = tid >> 6;
    const int m0 = blockIdx.y * 128, n0 = blockIdx.x * 128;
    const int wr = (wv >> 1) * 64, wc = (wv & 1) * 64;
    const int srow = lane >> 2;          // staging: 16 rows / 1KB chunk
    const int skk  = (lane & 3) * 8;     // 4 lanes x 16B per 64B row
    const int fr = lane & 15, fk = (lane >> 4) * 8;

    f32x4 acc[4][4] = {};

    for (int k0 = 0; k0 < K; k0 += 32) {
        #pragma unroll
        for (int rr = 0; rr < 2; ++rr) {
            const int c = wv * 2 + rr;          // wave-uniform chunk id
            const int row = c * 16 + srow;
            const bf16* ga = Ab + (long long)(m0 + row) * K + (k0 + skk);
            const bf16* gb = Bb + (long long)(n0 + row) * K + (k0 + skk);
            __builtin_amdgcn_global_load_lds(AS1(ga), AS3(ldsA + c * 512), 16, 0, 0);
            __builtin_amdgcn_global_load_lds(AS1(gb), AS3(ldsB + c * 512), 16, 0, 0);
        }
        __syncthreads();
        bf16x8 af[4], bfr[4];
        #pragma unroll
        for (int i = 0; i < 4; ++i)
            af[i] = *(const bf16x8*)(ldsA + (wr + i * 16 + fr) * 32 + fk);
        #pragma unroll
        for (int j = 0; j < 4; ++j)
            bfr[j] = *(const bf16x8*)(ldsB + (wc + j * 16 + fr) * 32 + fk);
        #pragma unroll
        for (int i = 0; i < 4; ++i)
            #pragma unroll
            for (int j = 0; j < 4; ++j)
                acc[i][j] = __builtin_amdgcn_mfma_f32_16x16x32_bf16(
                    af[i], bfr[j], acc[i][j], 0, 0, 0);
        __syncthreads();
    }

    // C/D layout: col = lane&15, row = (lane>>4)*4 + reg  [m89/m91-verified]
    const int erow = wr + (lane >> 4) * 4;
    const int ecol = wc + (lane & 15);
    #pragma unroll
    for (int i = 0; i < 4; ++i) {
        #pragma unroll
        for (int j = 0; j < 4; ++j) {
            #pragma unroll
            for (int r = 0; r < 4; ++r) {
                const long long row = m0 + erow + i * 16 + r;
                const long long col = n0 + ecol + j * 16;
                const long long idx = (long long)z * sC + row * N + col;
                const float v = acc[i][j][r];
                if (EPI == 0) {
                    ((bf16*)Cv)[idx] = __float2bfloat16(v);
                } else if (EPI == 1) {
                    const float g = __bfloat162float(Gaux[idx]);
                    const float sg_ = g / (1.f + __expf(-g));
                    ((bf16*)Cv)[idx] = __float2bfloat16(sg_ * v);
                } else {
                    ((float*)Cv)[idx] = v;
                }
            }
        }
    }
}

// ======================= 256x256 8-phase bf16 GEMM ===========================
// C[M,N] = A[M,K] @ B^T (B given [N][K]).  BM=BN=256, BK=64, 512 thr = 8 waves
// (2M x 4N), per-wave 128x64 output.  LDS 128 KiB: 2 dbuf x {A,B} x K-tile,
// stored K-slice-major [half(128r)][ks(32k)][row][32 cols] with XOR swizzle
// col ^= ((row>>3)&1)<<4  (st_16x32: byte-bit5 ^ row-bit3) applied BOTH on the
// pre-swizzled global_load_lds source and on the ds_read address (rule #21).
// Schedule per K-tile kt (buf d=kt&1), 4 phases, raw s_barrier, counted vmcnt:
//  ph1: ds A[i0..3,ks*] + B[j0..1,ks*] (12) | stage A-h0(kt+1)->d^1 | MFMA q00
//  ph2: ds B[j2..3,ks*] (4)                 | stage A-h1(kt+1)->d^1 | MFMA q01
//  ph3: ds A[i4..7,ks*] (8)                 | stage B-h0(kt+2)->d   | MFMA q10
//  ph4:                                     | stage B-h1(kt+2)->d   |
//       vmcnt(4)  (tile kt+1 complete; 2 half-tiles of kt+2 in flight) MFMA q11
// Race-safety: every buffer region is staged >=1 end-barrier after its last
// ds_read (B regions of buf d consumed by end of ph2; buf d^1 idle this tile).
template <int EPI>
__global__ __launch_bounds__(512, 2) void gemm256(
    const bf16* __restrict__ A, const bf16* __restrict__ B,
    void* __restrict__ Cv, const bf16* __restrict__ Gaux,
    int M, int N, int K, long long sA, long long sB, long long sC)
{
    __shared__ bf16 lds[2][2][16384];   // [dbuf][A/B][half*8192 + ks*4096 + row*32 + col]
    const int z = blockIdx.z;
    const bf16* Ab = A + (long long)z * sA;
    const bf16* Bb = B + (long long)z * sB;
    const int tid  = threadIdx.x;
    const int lane = tid & 63, wv = tid >> 6;       // 8 waves
    const int wm = wv >> 2, wn = wv & 3;            // 2 x 4 wave grid
    const int m0 = blockIdx.y * 256, n0 = blockIdx.x * 256;
    const int fr = lane & 15, fq = lane >> 4;       // fragment row / k-group

    // ---- staging: one half-tile (128 rows x 64 k) = 2 x global_load_lds ----
    const int srl  = (wv << 4) + (lane >> 2);       // row within half, 0..127
    const int sswz = ((srl >> 3) & 1) << 4;         // element XOR (16 bf16 = 32B)
    const int scol = ((lane & 3) << 3) ^ sswz;      // source k-col within 32-slice
    auto STAGE = [&](int d, int mx, int h, int kt) {
        const bf16* gb = (mx ? Bb : Ab);
        const int grow = (mx ? n0 : m0) + (h << 7) + srl;
        const bf16* g0 = gb + (long long)grow * K + (kt << 6) + scol;
        bf16* l0 = &lds[d][mx][(h << 13) + (wv << 9)];   // wave-uniform LDS base
        __builtin_amdgcn_global_load_lds(AS1(g0),      AS3(l0),        16, 0, 0);
        __builtin_amdgcn_global_load_lds(AS1(g0 + 32), AS3(l0 + 4096), 16, 0, 0);
    };
    // ---- swizzled fragment reads (ds_read_b128) ----
    auto LDA = [&](int d, int i, int ks) -> bf16x8 {
        const int row = i * 16 + fr;
        const int col = (fq << 3) ^ (((row >> 3) & 1) << 4);
        return *(const bf16x8*)&lds[d][0][(wm << 13) + (ks << 12) + row * 32 + col];
    };
    auto LDB = [&](int d, int j, int ks) -> bf16x8 {
        const int rr = wn * 64 + j * 16 + fr;       // 0..255
        const int h = rr >> 7, row = rr & 127;
        const int col = (fq << 3) ^ (((row >> 3) & 1) << 4);
        return *(const bf16x8*)&lds[d][1][(h << 13) + (ks << 12) + row * 32 + col];
    };

    f32x4 acc[8][4] = {};
    bf16x8 af[4][2], bfg[4][2];
    const int nkt = K >> 6;

    // ---- prologue: tile0 (A+B) and tile1 B halves ----
    STAGE(0, 0, 0, 0); STAGE(0, 0, 1, 0); STAGE(0, 1, 0, 0); STAGE(0, 1, 1, 0);
    if (nkt > 1) {
        STAGE(1, 1, 0, 1); STAGE(1, 1, 1, 1);
        asm volatile("s_waitcnt vmcnt(4)" ::: "memory");
    } else {
        asm volatile("s_waitcnt vmcnt(0)" ::: "memory");
    }
    asm volatile("s_barrier" ::: "memory");

    for (int kt = 0; kt < nkt; ++kt) {
        const int d = kt & 1;
        // ---------------- phase 1 ----------------
        #pragma unroll
        for (int i = 0; i < 4; ++i) { af[i][0] = LDA(d, i, 0); af[i][1] = LDA(d, i, 1); }
        #pragma unroll
        for (int j = 0; j < 2; ++j) { bfg[j][0] = LDB(d, j, 0); bfg[j][1] = LDB(d, j, 1); }
        if (kt + 1 < nkt) STAGE(d ^ 1, 0, 0, kt + 1);
        asm volatile("s_waitcnt lgkmcnt(8)" ::: "memory");
        asm volatile("s_barrier" ::: "memory");
        __builtin_amdgcn_s_setprio(1);
        #pragma unroll
        for (int i = 0; i < 4; ++i)
            #pragma unroll
            for (int j = 0; j < 2; ++j) {
                acc[i][j] = __builtin_amdgcn_mfma_f32_16x16x32_bf16(af[i][0], bfg[j][0], acc[i][j], 0, 0, 0);
                acc[i][j] = __builtin_amdgcn_mfma_f32_16x16x32_bf16(af[i][1], bfg[j][1], acc[i][j], 0, 0, 0);
            }
        __builtin_amdgcn_s_setprio(0);
        asm volatile("s_barrier" ::: "memory");
        // ---------------- phase 2 ----------------
        #pragma unroll
        for (int j = 2; j < 4; ++j) { bfg[j][0] = LDB(d, j, 0); bfg[j][1] = LDB(d, j, 1); }
        if (kt + 1 < nkt) STAGE(d ^ 1, 0, 1, kt + 1);
        asm volatile("s_barrier" ::: "memory");
        __builtin_amdgcn_s_setprio(1);
        #pragma unroll
        for (int i = 0; i < 4; ++i)
            #pragma unroll
            for (int j = 2; j < 4; ++j) {
                acc[i][j] = __builtin_amdgcn_mfma_f32_16x16x32_bf16(af[i][0], bfg[j][0], acc[i][j], 0, 0, 0);
                acc[i][j] = __builtin_amdgcn_mfma_f32_16x16x32_bf16(af[i][1], bfg[j][1], acc[i][j], 0, 0, 0);
            }
        __builtin_amdgcn_s_setprio(0);
        asm volatile("s_barrier" ::: "memory");
        // ---------------- phase 3 ----------------
        #pragma unroll
        for (int i = 0; i < 4; ++i) { af[i][0] = LDA(d, i + 4, 0); af[i][1] = LDA(d, i + 4, 1); }
        if (kt + 2 < nkt) STAGE(d, 1, 0, kt + 2);
        asm volatile("s_barrier" ::: "memory");
        __builtin_amdgcn_s_setprio(1);
        #pragma unroll
        for (int i = 0; i < 4; ++i)
            #pragma unroll
            for (int j = 0; j < 2; ++j) {
                acc[i + 4][j] = __builtin_amdgcn_mfma_f32_16x16x32_bf16(af[i][0], bfg[j][0], acc[i + 4][j], 0, 0, 0);
                acc[i + 4][j] = __builtin_amdgcn_mfma_f32_16x16x32_bf16(af[i][1], bfg[j][1], acc[i + 4][j], 0, 0, 0);
            }
        __builtin_amdgcn_s_setprio(0);
        asm volatile("s_barrier" ::: "memory");
        // ---------------- phase 4 ----------------
        if (kt + 2 < nkt) STAGE(d, 1, 1, kt + 2);
        if (kt + 1 < nkt) {
            if (kt + 2 < nkt) { asm volatile("s_waitcnt vmcnt(4)" ::: "memory"); }
            else              { asm volatile("s_waitcnt vmcnt(0)" ::: "memory"); }
        }
        asm volatile("s_barrier" ::: "memory");
        __builtin_amdgcn_s_setprio(1);
        #pragma unroll
        for (int i = 0; i < 4; ++i)
            #pragma unroll
            for (int j = 2; j < 4; ++j) {
                acc[i + 4][j] = __builtin_amdgcn_mfma_f32_16x16x32_bf16(af[i][0], bfg[j][0], acc[i + 4][j], 0, 0, 0);
                acc[i + 4][j] = __builtin_amdgcn_mfma_f32_16x16x32_bf16(af[i][1], bfg[j][1], acc[i + 4][j], 0, 0, 0);
            }
        __builtin_amdgcn_s_setprio(0);
        asm volatile("s_barrier" ::: "memory");
    }

    // ---- epilogue: C/D layout col=lane&15, row=(lane>>4)*4+reg ----
    const int erow0 = m0 + wm * 128 + fq * 4;
    const int ecol0 = n0 + wn * 64 + fr;
    #pragma unroll
    for (int i = 0; i < 8; ++i) {
        #pragma unroll
        for (int j = 0; j < 4; ++j) {
            #pragma unroll
            for (int r = 0; r < 4; ++r) {
                const long long row = erow0 + i * 16 + r;
                const long long col = ecol0 + j * 16;
                const long long idx = (long long)z * sC + row * N + col;
                const float v = acc[i][j][r];
                if (EPI == 0) {
                    ((bf16*)Cv)[idx] = __float2bfloat16(v);
                } else if (EPI == 1) {
                    const float g = __bfloat162float(Gaux[idx]);
                    const float sg_ = g / (1.f + __expf(-g));
                    ((bf16*)Cv)[idx] = __float2bfloat16(sg_ * v);
                } else {
                    ((float*)Cv)[idx] = v;
                }
            }
        }
    }
}

// ------------- combine: out = shared (already in d_out) + routed -------------
__global__ __launch_bounds__(256) void combine_kernel(
    float* __restrict__ out, const float* __restrict__ eout,
    const int* __restrict__ e0a, const int* __restrict__ e1a,
    const float* __restrict__ w0a, const float* __restrict__ w1a,
    const int* __restrict__ s0a, const int* __restrict__ s1a)
{
    const int t = blockIdx.x;
    const int tid = threadIdx.x;
    float4* op = (float4*)(out + (size_t)t * HDIM);
    float4 v = op[tid];
    const int s0 = s0a[t], s1 = s1a[t];
    if (s0 >= 0) {
        const float4* p = (const float4*)(eout + ((size_t)e0a[t] * CAP + s0) * HDIM);
        const float w = w0a[t];
        float4 c = p[tid];
        v.x += w * c.x; v.y += w * c.y; v.z += w * c.z; v.w += w * c.w;
    }
    if (s1 >= 0) {
        const float4* p = (const float4*)(eout + ((size_t)e1a[t] * CAP + s1) * HDIM);
        const float w = w1a[t];
        float4 c = p[tid];
        v.x += w * c.x; v.y += w * c.y; v.z += w * c.z; v.w += w * c.w;
    }
    op[tid] = v;
}

extern "C" void kernel_launch(void* const* d_in, const int* in_sizes, int n_in,
                              void* d_out, int out_size, void* d_ws, size_t ws_size,
                              hipStream_t stream)
{
    const float* x   = (const float*)d_in[0];
    const float* rtw = (const float*)d_in[1];
    const float* rg  = (const float*)d_in[2];
    const float* ru  = (const float*)d_in[3];
    const float* rd  = (const float*)d_in[4];
    const float* sg  = (const float*)d_in[5];
    const float* su  = (const float*)d_in[6];
    const float* sd  = (const float*)d_in[7];
    float* out = (float*)d_out;

    // workspace layout (~281 MB total)
    char* w = (char*)d_ws;
    auto alloc = [&](size_t n) { char* p = w; w += (n + 255) & ~(size_t)255; return p; };
    bf16*  xb   = (bf16*)alloc((size_t)TTOK * HDIM * 2);          // 16.8 MB
    bf16*  xg   = (bf16*)alloc((size_t)ENUM * CAP * HDIM * 2);    // 21.0 MB
    bf16*  gbuf = (bf16*)alloc((size_t)ENUM * CAP * IRD * 2);     // 83.9 MB (also shared-chunk h)
    float* eout = (float*)alloc((size_t)ENUM * CAP * HDIM * 4);   // 41.9 MB
    bf16*  wbuf = (bf16*)alloc((size_t)ENUM * HDIM * IRD * 2);    // 67.1 MB (reused rg/ru/rd)
    bf16*  sgt  = (bf16*)alloc((size_t)HDIM * ISH * 2);           // 16.8 MB
    bf16*  sut  = (bf16*)alloc((size_t)HDIM * ISH * 2);           // 16.8 MB
    bf16*  sdt  = (bf16*)alloc((size_t)HDIM * ISH * 2);           // 16.8 MB
    int*   e0a  = (int*)alloc(TTOK * 4);
    int*   e1a  = (int*)alloc(TTOK * 4);
    float* w0a  = (float*)alloc(TTOK * 4);
    float* w1a  = (float*)alloc(TTOK * 4);
    int*   s0a  = (int*)alloc(TTOK * 4);
    int*   s1a  = (int*)alloc(TTOK * 4);
    int*   disp = (int*)alloc(ENUM * CAP * 4);

    router_kernel<<<TTOK, 256, 0, stream>>>(x, rtw, xb, e0a, e1a, w0a, w1a, s0a, s1a);
    dispatch_kernel<<<ENUM, 256, 0, stream>>>(e0a, e1a, disp, s0a, s1a);
    gather_kernel<<<ENUM * CAP, 256, 0, stream>>>(disp, xb, xg);

    // ---- routed experts (batched over z = expert) ----
    tcvt_kernel<<<dim3(IRD / 32, HDIM / 32, ENUM), 256, 0, stream>>>(rg, wbuf, HDIM, IRD);
    gemm256<0><<<dim3(IRD / 256, CAP / 256, ENUM), 512, 0, stream>>>(
        xg, wbuf, gbuf, nullptr, CAP, IRD, HDIM,
        (long long)CAP * HDIM, (long long)IRD * HDIM, (long long)CAP * IRD);
    tcvt_kernel<<<dim3(IRD / 32, HDIM / 32, ENUM), 256, 0, stream>>>(ru, wbuf, HDIM, IRD);
    gemm256<1><<<dim3(IRD / 256, CAP / 256, ENUM), 512, 0, stream>>>(
        xg, wbuf, gbuf, gbuf, CAP, IRD, HDIM,
        (long long)CAP * HDIM, (long long)IRD * HDIM, (long long)CAP * IRD);
    tcvt_kernel<<<dim3(HDIM / 32, IRD / 32, ENUM), 256, 0, stream>>>(rd, wbuf, IRD, HDIM);
    gemm_bt<2><<<dim3(HDIM / 128, CAP / 128, ENUM), 256, 0, stream>>>(
        gbuf, wbuf, eout, nullptr, CAP, HDIM, IRD,
        (long long)CAP * IRD, (long long)HDIM * IRD, (long long)CAP * HDIM);

    // ---- shared expert, 2 chunks of 4096 rows (reuses gbuf) ----
    tcvt_kernel<<<dim3(ISH / 32, HDIM / 32, 1), 256, 0, stream>>>(sg, sgt, HDIM, ISH);
    tcvt_kernel<<<dim3(ISH / 32, HDIM / 32, 1), 256, 0, stream>>>(su, sut, HDIM, ISH);
    tcvt_kernel<<<dim3(HDIM / 32, ISH / 32, 1), 256, 0, stream>>>(sd, sdt, ISH, HDIM);
    for (int c = 0; c < 2; ++c) {
        const bf16* Ax = xb + (size_t)c * 4096 * HDIM;
        gemm256<0><<<dim3(ISH / 256, 4096 / 256, 1), 512, 0, stream>>>(
            Ax, sgt, gbuf, nullptr, 4096, ISH, HDIM, 0, 0, 0);
        gemm256<1><<<dim3(ISH / 256, 4096 / 256, 1), 512, 0, stream>>>(
            Ax, sut, gbuf, gbuf, 4096, ISH, HDIM, 0, 0, 0);
        gemm_bt<2><<<dim3(HDIM / 128, 4096 / 128, 1), 256, 0, stream>>>(
            gbuf, sdt, out + (size_t)c * 4096 * HDIM, nullptr, 4096, HDIM, ISH, 0, 0, 0);
    }
    combine_kernel<<<TTOK, 256, 0, stream>>>(out, eout, e0a, e1a, w0a, w1a, s0a, s1a);
}

// Round 2
// 1437.839 us; speedup vs baseline: 1.1171x; 1.1171x over previous
//
#include <hip/hip_runtime.h>
#include <hip/hip_bf16.h>

#define TTOK 8192
#define HDIM 1024
#define ENUM 8
#define CAP  1280
#define IRD  4096
#define ISH  8192

typedef __hip_bfloat16 bf16;
typedef __bf16 bf16x8 __attribute__((ext_vector_type(8)));
typedef float f32x4 __attribute__((ext_vector_type(4)));

#define AS1(p) ((const __attribute__((address_space(1))) void*)(p))
#define AS3(p) ((__attribute__((address_space(3))) void*)(p))

// ---------------- router: RMSNorm (f32) + logits (f32) + top-2 ----------------
// Also emits x as bf16 for the expert GEMMs (experts consume UN-normalized x).
__global__ __launch_bounds__(256) void router_kernel(
    const float* __restrict__ x, const float* __restrict__ rtw,
    bf16* __restrict__ xb,
    int* __restrict__ e0a, int* __restrict__ e1a,
    float* __restrict__ w0a, float* __restrict__ w1a,
    int* __restrict__ s0a, int* __restrict__ s1a)
{
    __shared__ float row[HDIM];
    __shared__ float ssred[4];
    __shared__ float lgl[ENUM];
    const int t = blockIdx.x;
    const int tid = threadIdx.x;
    const int lane = tid & 63, wv = tid >> 6;
    const float* xr = x + (size_t)t * HDIM;
    bf16* xbr = xb + (size_t)t * HDIM;
    float ss = 0.f;
    for (int i = tid; i < HDIM; i += 256) {
        float v = xr[i];
        row[i] = v;
        ss += v * v;
        xbr[i] = __float2bfloat16(v);
    }
    #pragma unroll
    for (int o = 32; o > 0; o >>= 1) ss += __shfl_down(ss, o, 64);
    if (lane == 0) ssred[wv] = ss;
    __syncthreads();
    // wave wv handles experts 2*wv and 2*wv+1 (E=8, 4 waves)
    for (int ee = 0; ee < 2; ++ee) {
        const int e = wv * 2 + ee;
        const float* we = rtw + e * HDIM;
        float p = 0.f;
        for (int i = lane; i < HDIM; i += 64) p += row[i] * we[i];
        #pragma unroll
        for (int o = 32; o > 0; o >>= 1) p += __shfl_down(p, o, 64);
        if (lane == 0) lgl[e] = p;
    }
    __syncthreads();
    if (tid == 0) {
        float tot = ssred[0] + ssred[1] + ssred[2] + ssred[3];
        float rstd = rsqrtf(tot / (float)HDIM + 1.1920929e-07f);
        float l[ENUM];
        #pragma unroll
        for (int e = 0; e < ENUM; ++e) l[e] = lgl[e] * rstd;
        int b0 = 0;
        #pragma unroll
        for (int e = 1; e < ENUM; ++e) if (l[e] > l[b0]) b0 = e;  // strict > = lowest idx on tie
        int b1 = (b0 == 0) ? 1 : 0;
        #pragma unroll
        for (int e = 0; e < ENUM; ++e) if (e != b0 && l[e] > l[b1]) b1 = e;
        // top-2 renormalized softmax == 2-way softmax over the top-2 logits
        float w0 = 1.f / (1.f + expf(l[b1] - l[b0]));
        e0a[t] = b0; e1a[t] = b1;
        w0a[t] = w0; w1a[t] = 1.f - w0;
        s0a[t] = -1; s1a[t] = -1;
    }
}

// ------------- dispatch: stable (token-order) compaction per expert -----------
__global__ __launch_bounds__(256) void dispatch_kernel(
    const int* __restrict__ e0a, const int* __restrict__ e1a,
    int* __restrict__ disp, int* __restrict__ s0a, int* __restrict__ s1a)
{
    const int e = blockIdx.x;
    const int tid = threadIdx.x;
    const int lane = tid & 63, wv = tid >> 6;
    __shared__ int wcnt[4];
    for (int i = tid; i < CAP; i += 256) disp[e * CAP + i] = 0;  // safe filler token
    __syncthreads();
    int run = 0;
    for (int base = 0; base < TTOK; base += 256) {
        const int t = base + tid;
        const bool f0 = (e0a[t] == e);
        const bool f1 = (e1a[t] == e);
        const bool f = f0 || f1;
        unsigned long long m = __ballot(f);
        int posw = __popcll(m & ((1ULL << lane) - 1ULL));
        if (lane == 0) wcnt[wv] = __popcll(m);
        __syncthreads();
        int off = 0;
        #pragma unroll
        for (int w = 0; w < 4; ++w) if (w < wv) off += wcnt[w];
        const int tot = wcnt[0] + wcnt[1] + wcnt[2] + wcnt[3];
        if (f) {
            const int pos = run + off + posw;
            if (pos < CAP) {          // tokens beyond capacity are dropped
                disp[e * CAP + pos] = t;
                if (f0) s0a[t] = pos; else s1a[t] = pos;
            }
        }
        run += tot;
        __syncthreads();
    }
}

// ----------------------------- gather x rows ---------------------------------
__global__ __launch_bounds__(256) void gather_kernel(
    const int* __restrict__ disp, const bf16* __restrict__ xb, bf16* __restrict__ xg)
{
    const int r = blockIdx.x;             // 0 .. E*CAP-1
    const int t = disp[r];
    const uint2* s = (const uint2*)(xb + (size_t)t * HDIM);
    uint2* d = (uint2*)(xg + (size_t)r * HDIM);
    d[threadIdx.x] = s[threadIdx.x];      // 256 * 8B = 2 KB row
}

// --------------- f32 -> bf16 transpose-convert (weights to [N][K]) -----------
__global__ __launch_bounds__(256) void tcvt_kernel(
    const float* __restrict__ in, bf16* __restrict__ out, int R, int C)
{
    __shared__ float tile[32][33];
    const size_t boff = (size_t)blockIdx.z * R * C;
    const int c0 = blockIdx.x * 32, r0 = blockIdx.y * 32;
    const int tx = threadIdx.x & 31, ty = threadIdx.x >> 5;
    #pragma unroll
    for (int i = 0; i < 4; ++i)
        tile[ty + i * 8][tx] = in[boff + (size_t)(r0 + ty + i * 8) * C + c0 + tx];
    __syncthreads();
    #pragma unroll
    for (int i = 0; i < 4; ++i)
        out[boff + (size_t)(c0 + ty + i * 8) * R + r0 + tx] =
            __float2bfloat16(tile[tx][ty + i * 8]);
}

// ======================= 256x256 8-phase bf16 GEMM ===========================
// C[M,N] = A[M,K] @ B^T (B given [N][K]).  BM=BN=256, BK=64, 512 thr = 8 waves
// (2M x 4N), per-wave 128x64 output.  LDS 128 KiB: 2 dbuf x {A,B} x K-tile,
// stored K-slice-major [half(128r)][ks(32k)][row][32 cols] with XOR swizzle
// col ^= ((row>>3)&1)<<4 applied BOTH on the pre-swizzled global_load_lds
// source and on the ds_read address (rule #21: both-sides-or-neither).
// Schedule per K-tile kt (buf d=kt&1), 4 phases, raw s_barrier, counted vmcnt:
//  ph1: ds A[i0..3,ks*] + B[j0..1,ks*] (12) | stage A-h0(kt+1)->d^1 | MFMA q00
//  ph2: ds B[j2..3,ks*] (4)                 | stage A-h1(kt+1)->d^1 | MFMA q01
//  ph3: ds A[i4..7,ks*] (8)                 | stage B-h0(kt+2)->d   | MFMA q10
//  ph4:                                     | stage B-h1(kt+2)->d   |
//       vmcnt(4)  (tile kt+1 complete; 2 half-tiles of kt+2 in flight) MFMA q11
// EPI: 0 = store bf16; 1 = silu(Gaux)*acc bf16; 2 = store f32; 3 = f32 +=.
template <int EPI>
__global__ __launch_bounds__(512, 2) void gemm256(
    const bf16* __restrict__ A, const bf16* __restrict__ B,
    void* __restrict__ Cv, const bf16* __restrict__ Gaux,
    int M, int N, int K, long long sA, long long sB, long long sC)
{
    __shared__ bf16 lds[2][2][16384];   // [dbuf][A/B][half*8192 + ks*4096 + row*32 + col]
    const int z = blockIdx.z;
    const bf16* Ab = A + (long long)z * sA;
    const bf16* Bb = B + (long long)z * sB;
    const int tid  = threadIdx.x;
    const int lane = tid & 63, wv = tid >> 6;       // 8 waves
    const int wm = wv >> 2, wn = wv & 3;            // 2 x 4 wave grid
    const int m0 = blockIdx.y * 256, n0 = blockIdx.x * 256;
    const int fr = lane & 15, fq = lane >> 4;       // fragment row / k-group

    // ---- staging: one half-tile (128 rows x 64 k) = 2 x global_load_lds ----
    const int srl  = (wv << 4) + (lane >> 2);       // row within half, 0..127
    const int sswz = ((srl >> 3) & 1) << 4;         // element XOR (16 bf16 = 32B)
    const int scol = ((lane & 3) << 3) ^ sswz;      // source k-col within 32-slice
    auto STAGE = [&](int d, int mx, int h, int kt) {
        const bf16* gb = (mx ? Bb : Ab);
        const int grow = (mx ? n0 : m0) + (h << 7) + srl;
        const bf16* g0 = gb + (long long)grow * K + (kt << 6) + scol;
        bf16* l0 = &lds[d][mx][(h << 13) + (wv << 9)];   // wave-uniform LDS base
        __builtin_amdgcn_global_load_lds(AS1(g0),      AS3(l0),        16, 0, 0);
        __builtin_amdgcn_global_load_lds(AS1(g0 + 32), AS3(l0 + 4096), 16, 0, 0);
    };
    // ---- swizzled fragment reads (ds_read_b128) ----
    auto LDA = [&](int d, int i, int ks) -> bf16x8 {
        const int row = i * 16 + fr;
        const int col = (fq << 3) ^ (((row >> 3) & 1) << 4);
        return *(const bf16x8*)&lds[d][0][(wm << 13) + (ks << 12) + row * 32 + col];
    };
    auto LDB = [&](int d, int j, int ks) -> bf16x8 {
        const int rr = wn * 64 + j * 16 + fr;       // 0..255
        const int h = rr >> 7, row = rr & 127;
        const int col = (fq << 3) ^ (((row >> 3) & 1) << 4);
        return *(const bf16x8*)&lds[d][1][(h << 13) + (ks << 12) + row * 32 + col];
    };

    f32x4 acc[8][4] = {};
    bf16x8 af[4][2], bfg[4][2];
    const int nkt = K >> 6;

    // ---- prologue: tile0 (A+B) and tile1 B halves ----
    STAGE(0, 0, 0, 0); STAGE(0, 0, 1, 0); STAGE(0, 1, 0, 0); STAGE(0, 1, 1, 0);
    if (nkt > 1) {
        STAGE(1, 1, 0, 1); STAGE(1, 1, 1, 1);
        asm volatile("s_waitcnt vmcnt(4)" ::: "memory");
    } else {
        asm volatile("s_waitcnt vmcnt(0)" ::: "memory");
    }
    asm volatile("s_barrier" ::: "memory");

    for (int kt = 0; kt < nkt; ++kt) {
        const int d = kt & 1;
        // ---------------- phase 1 ----------------
        #pragma unroll
        for (int i = 0; i < 4; ++i) { af[i][0] = LDA(d, i, 0); af[i][1] = LDA(d, i, 1); }
        #pragma unroll
        for (int j = 0; j < 2; ++j) { bfg[j][0] = LDB(d, j, 0); bfg[j][1] = LDB(d, j, 1); }
        if (kt + 1 < nkt) STAGE(d ^ 1, 0, 0, kt + 1);
        asm volatile("s_waitcnt lgkmcnt(8)" ::: "memory");
        asm volatile("s_barrier" ::: "memory");
        __builtin_amdgcn_s_setprio(1);
        #pragma unroll
        for (int i = 0; i < 4; ++i)
            #pragma unroll
            for (int j = 0; j < 2; ++j) {
                acc[i][j] = __builtin_amdgcn_mfma_f32_16x16x32_bf16(af[i][0], bfg[j][0], acc[i][j], 0, 0, 0);
                acc[i][j] = __builtin_amdgcn_mfma_f32_16x16x32_bf16(af[i][1], bfg[j][1], acc[i][j], 0, 0, 0);
            }
        __builtin_amdgcn_s_setprio(0);
        asm volatile("s_barrier" ::: "memory");
        // ---------------- phase 2 ----------------
        #pragma unroll
        for (int j = 2; j < 4; ++j) { bfg[j][0] = LDB(d, j, 0); bfg[j][1] = LDB(d, j, 1); }
        if (kt + 1 < nkt) STAGE(d ^ 1, 0, 1, kt + 1);
        asm volatile("s_barrier" ::: "memory");
        __builtin_amdgcn_s_setprio(1);
        #pragma unroll
        for (int i = 0; i < 4; ++i)
            #pragma unroll
            for (int j = 2; j < 4; ++j) {
                acc[i][j] = __builtin_amdgcn_mfma_f32_16x16x32_bf16(af[i][0], bfg[j][0], acc[i][j], 0, 0, 0);
                acc[i][j] = __builtin_amdgcn_mfma_f32_16x16x32_bf16(af[i][1], bfg[j][1], acc[i][j], 0, 0, 0);
            }
        __builtin_amdgcn_s_setprio(0);
        asm volatile("s_barrier" ::: "memory");
        // ---------------- phase 3 ----------------
        #pragma unroll
        for (int i = 0; i < 4; ++i) { af[i][0] = LDA(d, i + 4, 0); af[i][1] = LDA(d, i + 4, 1); }
        if (kt + 2 < nkt) STAGE(d, 1, 0, kt + 2);
        asm volatile("s_barrier" ::: "memory");
        __builtin_amdgcn_s_setprio(1);
        #pragma unroll
        for (int i = 0; i < 4; ++i)
            #pragma unroll
            for (int j = 0; j < 2; ++j) {
                acc[i + 4][j] = __builtin_amdgcn_mfma_f32_16x16x32_bf16(af[i][0], bfg[j][0], acc[i + 4][j], 0, 0, 0);
                acc[i + 4][j] = __builtin_amdgcn_mfma_f32_16x16x32_bf16(af[i][1], bfg[j][1], acc[i + 4][j], 0, 0, 0);
            }
        __builtin_amdgcn_s_setprio(0);
        asm volatile("s_barrier" ::: "memory");
        // ---------------- phase 4 ----------------
        if (kt + 2 < nkt) STAGE(d, 1, 1, kt + 2);
        if (kt + 1 < nkt) {
            if (kt + 2 < nkt) { asm volatile("s_waitcnt vmcnt(4)" ::: "memory"); }
            else              { asm volatile("s_waitcnt vmcnt(0)" ::: "memory"); }
        }
        asm volatile("s_barrier" ::: "memory");
        __builtin_amdgcn_s_setprio(1);
        #pragma unroll
        for (int i = 0; i < 4; ++i)
            #pragma unroll
            for (int j = 2; j < 4; ++j) {
                acc[i + 4][j] = __builtin_amdgcn_mfma_f32_16x16x32_bf16(af[i][0], bfg[j][0], acc[i + 4][j], 0, 0, 0);
                acc[i + 4][j] = __builtin_amdgcn_mfma_f32_16x16x32_bf16(af[i][1], bfg[j][1], acc[i + 4][j], 0, 0, 0);
            }
        __builtin_amdgcn_s_setprio(0);
        asm volatile("s_barrier" ::: "memory");
    }

    // ---- epilogue: C/D layout col=lane&15, row=(lane>>4)*4+reg ----
    const int erow0 = m0 + wm * 128 + fq * 4;
    const int ecol0 = n0 + wn * 64 + fr;
    #pragma unroll
    for (int i = 0; i < 8; ++i) {
        #pragma unroll
        for (int j = 0; j < 4; ++j) {
            #pragma unroll
            for (int r = 0; r < 4; ++r) {
                const long long row = erow0 + i * 16 + r;
                const long long col = ecol0 + j * 16;
                const long long idx = (long long)z * sC + row * N + col;
                const float v = acc[i][j][r];
                if (EPI == 0) {
                    ((bf16*)Cv)[idx] = __float2bfloat16(v);
                } else if (EPI == 1) {
                    const float g = __bfloat162float(Gaux[idx]);
                    const float sg_ = g / (1.f + __expf(-g));
                    ((bf16*)Cv)[idx] = __float2bfloat16(sg_ * v);
                } else if (EPI == 2) {
                    ((float*)Cv)[idx] = v;
                } else {
                    ((float*)Cv)[idx] += v;   // K-split accumulate (dispatches serialize)
                }
            }
        }
    }
}

// ------------- combine: out = shared (already in d_out) + routed -------------
__global__ __launch_bounds__(256) void combine_kernel(
    float* __restrict__ out, const float* __restrict__ eout,
    const int* __restrict__ e0a, const int* __restrict__ e1a,
    const float* __restrict__ w0a, const float* __restrict__ w1a,
    const int* __restrict__ s0a, const int* __restrict__ s1a)
{
    const int t = blockIdx.x;
    const int tid = threadIdx.x;
    float4* op = (float4*)(out + (size_t)t * HDIM);
    float4 v = op[tid];
    const int s0 = s0a[t], s1 = s1a[t];
    if (s0 >= 0) {
        const float4* p = (const float4*)(eout + ((size_t)e0a[t] * CAP + s0) * HDIM);
        const float w = w0a[t];
        float4 c = p[tid];
        v.x += w * c.x; v.y += w * c.y; v.z += w * c.z; v.w += w * c.w;
    }
    if (s1 >= 0) {
        const float4* p = (const float4*)(eout + ((size_t)e1a[t] * CAP + s1) * HDIM);
        const float w = w1a[t];
        float4 c = p[tid];
        v.x += w * c.x; v.y += w * c.y; v.z += w * c.z; v.w += w * c.w;
    }
    op[tid] = v;
}

extern "C" void kernel_launch(void* const* d_in, const int* in_sizes, int n_in,
                              void* d_out, int out_size, void* d_ws, size_t ws_size,
                              hipStream_t stream)
{
    const float* x   = (const float*)d_in[0];
    const float* rtw = (const float*)d_in[1];
    const float* rg  = (const float*)d_in[2];
    const float* ru  = (const float*)d_in[3];
    const float* rd  = (const float*)d_in[4];
    const float* sg  = (const float*)d_in[5];
    const float* su  = (const float*)d_in[6];
    const float* sd  = (const float*)d_in[7];
    float* out = (float*)d_out;

    // workspace layout (~281 MB total)
    char* w = (char*)d_ws;
    auto alloc = [&](size_t n) { char* p = w; w += (n + 255) & ~(size_t)255; return p; };
    bf16*  xb   = (bf16*)alloc((size_t)TTOK * HDIM * 2);          // 16.8 MB
    bf16*  xg   = (bf16*)alloc((size_t)ENUM * CAP * HDIM * 2);    // 21.0 MB
    bf16*  gbuf = (bf16*)alloc((size_t)ENUM * CAP * IRD * 2);     // 83.9 MB (also shared h-chunk [8192][4096] = 67 MB)
    float* eout = (float*)alloc((size_t)ENUM * CAP * HDIM * 4);   // 41.9 MB
    bf16*  wbuf = (bf16*)alloc((size_t)ENUM * HDIM * IRD * 2);    // 67.1 MB (reused rg/ru/rd)
    bf16*  sgt  = (bf16*)alloc((size_t)HDIM * ISH * 2);           // 16.8 MB  [ISH][HDIM]
    bf16*  sut  = (bf16*)alloc((size_t)HDIM * ISH * 2);           // 16.8 MB  [ISH][HDIM]
    bf16*  sdt  = (bf16*)alloc((size_t)HDIM * ISH * 2);           // 16.8 MB  [2][HDIM][4096] chunk-major
    int*   e0a  = (int*)alloc(TTOK * 4);
    int*   e1a  = (int*)alloc(TTOK * 4);
    float* w0a  = (float*)alloc(TTOK * 4);
    float* w1a  = (float*)alloc(TTOK * 4);
    int*   s0a  = (int*)alloc(TTOK * 4);
    int*   s1a  = (int*)alloc(TTOK * 4);
    int*   disp = (int*)alloc(ENUM * CAP * 4);

    router_kernel<<<TTOK, 256, 0, stream>>>(x, rtw, xb, e0a, e1a, w0a, w1a, s0a, s1a);
    dispatch_kernel<<<ENUM, 256, 0, stream>>>(e0a, e1a, disp, s0a, s1a);
    gather_kernel<<<ENUM * CAP, 256, 0, stream>>>(disp, xb, xg);

    // ---- routed experts (batched over z = expert), all on gemm256 ----
    tcvt_kernel<<<dim3(IRD / 32, HDIM / 32, ENUM), 256, 0, stream>>>(rg, wbuf, HDIM, IRD);
    gemm256<0><<<dim3(IRD / 256, CAP / 256, ENUM), 512, 0, stream>>>(
        xg, wbuf, gbuf, nullptr, CAP, IRD, HDIM,
        (long long)CAP * HDIM, (long long)IRD * HDIM, (long long)CAP * IRD);
    tcvt_kernel<<<dim3(IRD / 32, HDIM / 32, ENUM), 256, 0, stream>>>(ru, wbuf, HDIM, IRD);
    gemm256<1><<<dim3(IRD / 256, CAP / 256, ENUM), 512, 0, stream>>>(
        xg, wbuf, gbuf, gbuf, CAP, IRD, HDIM,
        (long long)CAP * HDIM, (long long)IRD * HDIM, (long long)CAP * IRD);
    tcvt_kernel<<<dim3(HDIM / 32, IRD / 32, ENUM), 256, 0, stream>>>(rd, wbuf, IRD, HDIM);
    gemm256<2><<<dim3(HDIM / 256, CAP / 256, ENUM), 512, 0, stream>>>(
        gbuf, wbuf, eout, nullptr, CAP, HDIM, IRD,
        (long long)CAP * IRD, (long long)HDIM * IRD, (long long)CAP * HDIM);

    // ---- shared expert: chunk ISH (not M) into 2 halves of 4096 ----
    // gate/up at full M=8192 over an N-half (h chunk = 67 MB, fits gbuf);
    // down becomes a K-split: chunk 0 stores f32, chunk 1 accumulates (+=).
    tcvt_kernel<<<dim3(ISH / 32, HDIM / 32, 1), 256, 0, stream>>>(sg, sgt, HDIM, ISH);
    tcvt_kernel<<<dim3(ISH / 32, HDIM / 32, 1), 256, 0, stream>>>(su, sut, HDIM, ISH);
    // sd chunk-major transpose: sdt = [2][HDIM][4096], sdt[c][n][k] = sd[c*4096+k][n]
    for (int c = 0; c < 2; ++c)
        tcvt_kernel<<<dim3(HDIM / 32, 4096 / 32, 1), 256, 0, stream>>>(
            sd + (size_t)c * 4096 * HDIM, sdt + (size_t)c * HDIM * 4096, 4096, HDIM);
    for (int c = 0; c < 2; ++c) {
        const bf16* Bg = sgt + (size_t)c * 4096 * HDIM;
        const bf16* Bu = sut + (size_t)c * 4096 * HDIM;
        const bf16* Bd = sdt + (size_t)c * HDIM * 4096;
        gemm256<0><<<dim3(4096 / 256, TTOK / 256, 1), 512, 0, stream>>>(
            xb, Bg, gbuf, nullptr, TTOK, 4096, HDIM, 0, 0, 0);
        gemm256<1><<<dim3(4096 / 256, TTOK / 256, 1), 512, 0, stream>>>(
            xb, Bu, gbuf, gbuf, TTOK, 4096, HDIM, 0, 0, 0);
        if (c == 0)
            gemm256<2><<<dim3(HDIM / 256, TTOK / 256, 1), 512, 0, stream>>>(
                gbuf, Bd, out, nullptr, TTOK, HDIM, 4096, 0, 0, 0);
        else
            gemm256<3><<<dim3(HDIM / 256, TTOK / 256, 1), 512, 0, stream>>>(
                gbuf, Bd, out, nullptr, TTOK, HDIM, 4096, 0, 0, 0);
    }
    combine_kernel<<<TTOK, 256, 0, stream>>>(out, eout, e0a, e1a, w0a, w1a, s0a, s1a);
}